// Round 4
// baseline (242.039 us; speedup 1.0000x reference)
//
#include <hip/hip_runtime.h>
#include <hip/hip_bf16.h>
#include <hip/hip_cooperative_groups.h>

namespace cg = cooperative_groups;

#define N_ROWS 4096
#define D_FULL 1024
#define DHALF  512
#define GSPLIT 16

typedef __attribute__((ext_vector_type(8))) short bf16x8;
typedef __attribute__((ext_vector_type(8))) unsigned short u16x8;
typedef __attribute__((ext_vector_type(4))) float f32x4;

__device__ __forceinline__ unsigned short f2b(float f) {
  __hip_bfloat16 h = __float2bfloat16(f);
  union { __hip_bfloat16 b; unsigned short u; } cv;
  cv.b = h;
  return cv.u;
}
__device__ __forceinline__ float b2f(unsigned short u) {
  union { unsigned int i; float f; } cv;
  cv.i = ((unsigned int)u) << 16;
  return cv.f;
}

// async global -> LDS: wave-uniform LDS base, lane i lands at base + i*16B
__device__ __forceinline__ void load_lds16(const void* g, void* l) {
  __builtin_amdgcn_global_load_lds(
      (const __attribute__((address_space(1))) unsigned int*)g,
      (__attribute__((address_space(3))) unsigned int*)l, 16, 0, 0);
}

// ================= fused conversion: x -> xb,xT  and 6 weights -> Wb,WbT =================
__device__ __forceinline__ void cvt_tile(const float* __restrict__ src, int lds_,
                                         unsigned short* __restrict__ dst, int ldd,
                                         unsigned short* __restrict__ dstT, int ldt,
                                         int n0, int c0) {
  __shared__ unsigned short tile[64][66];
  const int t  = threadIdx.x;
  const int r  = t >> 2;
  const int cq = (t & 3) * 16;

  unsigned short loc[16];
  #pragma unroll
  for (int i = 0; i < 4; ++i) {
    float4 v = *reinterpret_cast<const float4*>(&src[(size_t)(n0 + r) * lds_ + c0 + cq + i * 4]);
    loc[i*4+0] = f2b(v.x); loc[i*4+1] = f2b(v.y); loc[i*4+2] = f2b(v.z); loc[i*4+3] = f2b(v.w);
  }
  {
    u16x8 a, b;
    #pragma unroll
    for (int i = 0; i < 8; ++i) { a[i] = loc[i]; b[i] = loc[8+i]; }
    unsigned short* p = &dst[(size_t)(n0 + r) * ldd + c0 + cq];
    *reinterpret_cast<u16x8*>(p)     = a;
    *reinterpret_cast<u16x8*>(p + 8) = b;
  }
  #pragma unroll
  for (int i = 0; i < 8; ++i) {
    ushort2 w2; w2.x = loc[2*i]; w2.y = loc[2*i+1];
    *reinterpret_cast<ushort2*>(&tile[r][cq + 2*i]) = w2;
  }
  __syncthreads();
  const int c  = t >> 2;
  const int ng = (t & 3) * 16;
  unsigned short o[16];
  #pragma unroll
  for (int i = 0; i < 16; ++i) o[i] = tile[ng + i][c];
  u16x8 a, b;
  #pragma unroll
  for (int i = 0; i < 8; ++i) { a[i] = o[i]; b[i] = o[8+i]; }
  unsigned short* p = &dstT[(size_t)(c0 + c) * ldt + n0 + ng];
  *reinterpret_cast<u16x8*>(p)     = a;
  *reinterpret_cast<u16x8*>(p + 8) = b;
}

__global__ __launch_bounds__(256) void k_cvt_all(const float* __restrict__ x,
                                                 const float* __restrict__ w0, const float* __restrict__ w1,
                                                 const float* __restrict__ w2, const float* __restrict__ w3,
                                                 const float* __restrict__ w4, const float* __restrict__ w5,
                                                 unsigned short* __restrict__ xb,
                                                 unsigned short* __restrict__ xT,
                                                 unsigned short* __restrict__ Wb,
                                                 unsigned short* __restrict__ WbT) {
  const int b = blockIdx.x;
  if (b < 1024) {
    cvt_tile(x, D_FULL, xb, D_FULL, xT, N_ROWS, (b >> 4) * 64, (b & 15) * 64);
  } else {
    const int b2 = b - 1024;
    const int z = b2 >> 6, t = b2 & 63;
    const float* w;
    switch (z) {
      case 0: w = w0; break; case 1: w = w1; break; case 2: w = w2; break;
      case 3: w = w3; break; case 4: w = w4; break; default: w = w5; break;
    }
    const size_t HH = (size_t)DHALF * DHALF;
    cvt_tile(w, DHALF, Wb + z * HH, DHALF, WbT + z * HH, DHALF, (t >> 3) * 64, (t & 7) * 64);
  }
}

// ================= big GEMM (gram): C[m][n] = sum_k A[m][k]*B[n][k], m97 structure =================
__global__ __launch_bounds__(256) void k_big(const unsigned short* __restrict__ A,
                                             const unsigned short* __restrict__ B,
                                             unsigned short* __restrict__ C,
                                             int lda, int ldb, int ldc, int kLen, int nSplit,
                                             long long hA, long long sA,
                                             long long hB, long long sB,
                                             long long hC, long long sC) {
  const int z = blockIdx.z;
  const int h = z / nSplit, s = z % nSplit;
  const unsigned short* Ab = A + (size_t)h * hA + (size_t)s * sA;
  const unsigned short* Bb = B + (size_t)h * hB + (size_t)s * sB;
  unsigned short* Cb = C + (size_t)h * hC + (size_t)s * sC;
  const int n0 = blockIdx.x * 128;
  const int m0 = blockIdx.y * 128;

  __shared__ __align__(16) unsigned short lds[2][2][128 * 32];

  const int tid  = threadIdx.x;
  const int lane = tid & 63;
  const int wave = tid >> 6;
  const int wm = (wave >> 1) * 64;
  const int wn = (wave & 1) * 64;
  const int fr = lane & 15;
  const int kg = (lane >> 4) * 8;

  const int srow = wave * 32 + (lane >> 2);
  const int scol = (lane & 3) * 8;
  const unsigned short* gA0 = Ab + (size_t)(m0 + srow) * lda + scol;
  const unsigned short* gA1 = gA0 + (size_t)16 * lda;
  const unsigned short* gB0 = Bb + (size_t)(n0 + srow) * ldb + scol;
  const unsigned short* gB1 = gB0 + (size_t)16 * ldb;
  const int stOff = wave * 1024;

  f32x4 acc[4][4] = {};

  auto STAGE = [&](int buf, int kofs) {
    load_lds16(gA0 + kofs, &lds[buf][0][stOff]);
    load_lds16(gA1 + kofs, &lds[buf][0][stOff + 512]);
    load_lds16(gB0 + kofs, &lds[buf][1][stOff]);
    load_lds16(gB1 + kofs, &lds[buf][1][stOff + 512]);
  };
  auto COMPUTE = [&](int buf) {
    const unsigned short* la = &lds[buf][0][0];
    const unsigned short* lb = &lds[buf][1][0];
    bf16x8 af[4], bf[4];
    #pragma unroll
    for (int f = 0; f < 4; ++f) {
      af[f] = *reinterpret_cast<const bf16x8*>(&la[(wm + f * 16 + fr) * 32 + kg]);
      bf[f] = *reinterpret_cast<const bf16x8*>(&lb[(wn + f * 16 + fr) * 32 + kg]);
    }
    #pragma unroll
    for (int fm = 0; fm < 4; ++fm)
      #pragma unroll
      for (int fn = 0; fn < 4; ++fn)
        acc[fm][fn] = __builtin_amdgcn_mfma_f32_16x16x32_bf16(af[fm], bf[fn], acc[fm][fn], 0, 0, 0);
  };

  const int nt = kLen >> 5;
  STAGE(0, 0);
  __syncthreads();
  for (int t = 0; t < nt - 1; ++t) {
    STAGE((t + 1) & 1, (t + 1) * 32);
    COMPUTE(t & 1);
    __syncthreads();
  }
  COMPUTE((nt - 1) & 1);

  #pragma unroll
  for (int fm = 0; fm < 4; ++fm)
    #pragma unroll
    for (int fn = 0; fn < 4; ++fn)
      #pragma unroll
      for (int r = 0; r < 4; ++r) {
        int row = m0 + wm + fm * 16 + (lane >> 4) * 4 + r;
        int col = n0 + wn + fn * 16 + fr;
        Cb[(size_t)row * ldc + col] = f2b(acc[fm][fn][r]);
      }
}

// ================= device: 64x64-tile 512^3 GEMM step, C[m][n] = sum_k A[m][k]*B[n][k] =================
// SH: 32768 ushorts (64 KB). Layout: [buf][op][panel][2048].
__device__ __forceinline__ void gemm64(const unsigned short* __restrict__ Ab,
                                       const unsigned short* __restrict__ Bb,
                                       unsigned short* __restrict__ Cb,
                                       int m0, int n0, unsigned short* SH) {
  const int tid  = threadIdx.x;
  const int lane = tid & 63;
  const int wave = tid >> 6;
  const int wm = (wave >> 1) * 32;
  const int wn = (wave & 1) * 32;
  const int fr = lane & 15;
  const int kg = (lane >> 4) * 8;

  const int srow = lane >> 2;
  const int scol = (lane & 3) * 8;
  const unsigned short* gA = Ab + (size_t)(m0 + srow) * DHALF + wave * 32 + scol;
  const unsigned short* gB = Bb + (size_t)(n0 + srow) * DHALF + wave * 32 + scol;

  auto L = [&](int buf, int op, int p) -> unsigned short* {
    return SH + (((buf * 2 + op) * 4 + p) << 11);
  };

  f32x4 acc[2][2] = {};

  auto STAGE = [&](int buf, int kofs) {
    #pragma unroll
    for (int j = 0; j < 4; ++j) {
      load_lds16(gA + kofs + j * 16 * DHALF, L(buf, 0, wave) + j * 512);
      load_lds16(gB + kofs + j * 16 * DHALF, L(buf, 1, wave) + j * 512);
    }
  };
  auto COMPUTE = [&](int buf) {
    #pragma unroll
    for (int p = 0; p < 4; ++p) {
      bf16x8 a0 = *reinterpret_cast<const bf16x8*>(&L(buf,0,p)[(wm + fr) * 32 + kg]);
      bf16x8 a1 = *reinterpret_cast<const bf16x8*>(&L(buf,0,p)[(wm + 16 + fr) * 32 + kg]);
      bf16x8 b0 = *reinterpret_cast<const bf16x8*>(&L(buf,1,p)[(wn + fr) * 32 + kg]);
      bf16x8 b1 = *reinterpret_cast<const bf16x8*>(&L(buf,1,p)[(wn + 16 + fr) * 32 + kg]);
      acc[0][0] = __builtin_amdgcn_mfma_f32_16x16x32_bf16(a0, b0, acc[0][0], 0, 0, 0);
      acc[0][1] = __builtin_amdgcn_mfma_f32_16x16x32_bf16(a0, b1, acc[0][1], 0, 0, 0);
      acc[1][0] = __builtin_amdgcn_mfma_f32_16x16x32_bf16(a1, b0, acc[1][0], 0, 0, 0);
      acc[1][1] = __builtin_amdgcn_mfma_f32_16x16x32_bf16(a1, b1, acc[1][1], 0, 0, 0);
    }
  };

  STAGE(0, 0);
  __syncthreads();
  for (int t = 0; t < 3; ++t) {
    STAGE((t + 1) & 1, (t + 1) * 128);
    COMPUTE(t & 1);
    __syncthreads();
  }
  COMPUTE(1);

  #pragma unroll
  for (int fm = 0; fm < 2; ++fm)
    #pragma unroll
    for (int fn = 0; fn < 2; ++fn)
      #pragma unroll
      for (int r = 0; r < 4; ++r) {
        int row = m0 + wm + fm * 16 + (lane >> 4) * 4 + r;
        int col = n0 + wn + fn * 16 + fr;
        Cb[(size_t)row * DHALF + col] = f2b(acc[fm][fn][r]);
      }
}

// ================= device: final 128x64-tile GEMM, out[m][hoff+n] = sum_d xb[m][hoff+d]*MT[n][d] ====
__device__ __forceinline__ void gemm_final(const unsigned short* __restrict__ xb,
                                           const unsigned short* __restrict__ MTh,
                                           float* __restrict__ out,
                                           int m0, int n0, int hoff, unsigned short* SH) {
  const int tid  = threadIdx.x;
  const int lane = tid & 63;
  const int wave = tid >> 6;
  const int wm = (wave >> 1) * 64;
  const int wn = (wave & 1) * 32;
  const int fr = lane & 15;
  const int kg = (lane >> 4) * 8;

  const int srow = wave * 32 + (lane >> 2);
  const int scol = (lane & 3) * 8;
  const unsigned short* gA0 = xb + (size_t)(m0 + srow) * D_FULL + hoff + scol;
  const unsigned short* gA1 = gA0 + (size_t)16 * D_FULL;
  const int brow = wave * 16 + (lane >> 2);
  const unsigned short* gB = MTh + (size_t)(n0 + brow) * DHALF + scol;

  // SH layout: A[buf] at buf*4096 (128x32), B[buf] at 8192 + buf*2048 (64x32)
  f32x4 acc[4][2] = {};

  auto STAGE = [&](int buf, int kofs) {
    unsigned short* A = SH + buf * 4096;
    unsigned short* B = SH + 8192 + buf * 2048;
    load_lds16(gA0 + kofs, A + wave * 1024);
    load_lds16(gA1 + kofs, A + wave * 1024 + 512);
    load_lds16(gB + kofs, B + wave * 512);
  };
  auto COMPUTE = [&](int buf) {
    unsigned short* A = SH + buf * 4096;
    unsigned short* B = SH + 8192 + buf * 2048;
    bf16x8 af[4], bv[2];
    #pragma unroll
    for (int f = 0; f < 4; ++f)
      af[f] = *reinterpret_cast<const bf16x8*>(&A[(wm + f * 16 + fr) * 32 + kg]);
    #pragma unroll
    for (int f = 0; f < 2; ++f)
      bv[f] = *reinterpret_cast<const bf16x8*>(&B[(wn + f * 16 + fr) * 32 + kg]);
    #pragma unroll
    for (int fm = 0; fm < 4; ++fm)
      #pragma unroll
      for (int fn = 0; fn < 2; ++fn)
        acc[fm][fn] = __builtin_amdgcn_mfma_f32_16x16x32_bf16(af[fm], bv[fn], acc[fm][fn], 0, 0, 0);
  };

  STAGE(0, 0);
  __syncthreads();
  for (int t = 0; t < 15; ++t) {
    STAGE((t + 1) & 1, (t + 1) * 32);
    COMPUTE(t & 1);
    __syncthreads();
  }
  COMPUTE(1);

  #pragma unroll
  for (int fm = 0; fm < 4; ++fm)
    #pragma unroll
    for (int fn = 0; fn < 2; ++fn)
      #pragma unroll
      for (int r = 0; r < 4; ++r) {
        int row = m0 + wm + fm * 16 + (lane >> 4) * 4 + r;
        int col = hoff + n0 + wn + fn * 16 + fr;
        out[(size_t)row * D_FULL + col] = acc[fm][fn][r];
      }
}

// ================= cooperative chain: [gred || P] -> TT -> MT -> final =================
__global__ __launch_bounds__(256, 2) void k_chain(const unsigned short* __restrict__ Wb,
                                                  const unsigned short* __restrict__ WbT,
                                                  const unsigned short* __restrict__ Gp,
                                                  unsigned short* __restrict__ G,
                                                  unsigned short* __restrict__ P,
                                                  unsigned short* __restrict__ TT,
                                                  unsigned short* __restrict__ MT,
                                                  const unsigned short* __restrict__ xb,
                                                  float* __restrict__ out) {
  __shared__ __align__(16) unsigned short SH[32768];   // 64 KB
  cg::grid_group grid = cg::this_grid();
  const int b = blockIdx.x;
  const long long HH = 262144;

  // ---- Phase A: blocks 0..127 -> P = WqT * (WkT)^T ; blocks 128..383 -> gred ----
  if (b < 128) {
    const int h = b >> 6, rem = b & 63;
    gemm64(WbT + h * HH, WbT + (2 + h) * HH, P + h * HH, (rem >> 3) * 64, (rem & 7) * 64, SH);
  } else if (b < 384) {
    const int gid = (b - 128) * 256 + threadIdx.x;     // 0..65535
    const int h = gid >> 15;
    const size_t e = (size_t)(gid & 32767) * 8;
    const size_t base = (size_t)h * GSPLIT * HH + e;
    float sum[8] = {};
    #pragma unroll
    for (int s = 0; s < GSPLIT; ++s) {
      u16x8 v = *reinterpret_cast<const u16x8*>(&Gp[base + (size_t)s * HH]);
      #pragma unroll
      for (int i = 0; i < 8; ++i) sum[i] += b2f(v[i]);
    }
    u16x8 o;
    #pragma unroll
    for (int i = 0; i < 8; ++i) o[i] = f2b(sum[i]);
    *reinterpret_cast<u16x8*>(&G[(size_t)h * HH + e]) = o;
  }
  grid.sync();

  // ---- Phase B: TT = Wv * G (G symmetric) ----
  if (b < 128) {
    const int h = b >> 6, rem = b & 63;
    gemm64(Wb + (4 + h) * HH, G + h * HH, TT + h * HH, (rem >> 3) * 64, (rem & 7) * 64, SH);
  }
  grid.sync();

  // ---- Phase C: MT = TT * P^T ----
  if (b < 128) {
    const int h = b >> 6, rem = b & 63;
    gemm64(TT + h * HH, P + h * HH, MT + h * HH, (rem >> 3) * 64, (rem & 7) * 64, SH);
  }
  grid.sync();

  // ---- Phase D: out = X_h * M_h  (all 512 blocks, 128x64 tiles) ----
  {
    const int h = b >> 8, rem = b & 255;
    gemm_final(xb, MT + h * HH, out, (rem >> 3) * 128, (rem & 7) * 64, h * DHALF, SH);
  }
}

extern "C" void kernel_launch(void* const* d_in, const int* in_sizes, int n_in,
                              void* d_out, int out_size, void* d_ws, size_t ws_size,
                              hipStream_t stream) {
  const float* x   = (const float*)d_in[0];
  const float* Wq1 = (const float*)d_in[1];
  const float* Wq2 = (const float*)d_in[2];
  const float* Wk1 = (const float*)d_in[3];
  const float* Wk2 = (const float*)d_in[4];
  const float* Wv1 = (const float*)d_in[5];
  const float* Wv2 = (const float*)d_in[6];
  float* out = (float*)d_out;

  // workspace layout (ushort elements), ~44 MB
  unsigned short* ws  = (unsigned short*)d_ws;
  unsigned short* xb  = ws;                    // [4096][1024]
  unsigned short* xT  = ws + 4194304;          // [1024][4096]
  unsigned short* Wb  = ws + 8388608;          // 6x[512][512]: q1,q2,k1,k2,v1,v2
  unsigned short* WbT = ws + 9961472;          // transposes, same order
  unsigned short* G   = ws + 11534336;         // [2][512][512]
  unsigned short* P   = ws + 12058624;         // [2][512][512]
  unsigned short* TT  = ws + 12582912;         // [2][512][512]
  unsigned short* MT  = ws + 13107200;         // [2][512][512]
  unsigned short* Gp  = ws + 13631488;         // [2*GSPLIT][512][512] bf16 partials

  const long long HH = 262144;

  k_cvt_all<<<1408, 256, 0, stream>>>(x, Wq1, Wq2, Wk1, Wk2, Wv1, Wv2, xb, xT, Wb, WbT);

  // Gram partials: Gp[h*16+s] = X_h(s-chunk)^T X_h(s-chunk)
  k_big<<<dim3(4, 4, 2 * GSPLIT), 256, 0, stream>>>(
      xT, xT, Gp, N_ROWS, N_ROWS, DHALF, N_ROWS / GSPLIT, GSPLIT,
      (long long)DHALF * N_ROWS, N_ROWS / GSPLIT,
      (long long)DHALF * N_ROWS, N_ROWS / GSPLIT,
      GSPLIT * HH, HH);

  {
    void* args[] = { (void*)&Wb, (void*)&WbT, (void*)&Gp, (void*)&G, (void*)&P,
                     (void*)&TT, (void*)&MT, (void*)&xb, (void*)&out };
    hipLaunchCooperativeKernel((const void*)k_chain, dim3(512), dim3(256), args, 0, stream);
  }
}

// Round 5
// 60.869 us; speedup vs baseline: 3.9764x; 3.9764x over previous
//
#include <hip/hip_runtime.h>
#include <hip/hip_bf16.h>

#define N_ROWS 4096
#define D_FULL 1024
#define DHALF  512
#define GSPLIT 16

typedef __attribute__((ext_vector_type(8))) short bf16x8;
typedef __attribute__((ext_vector_type(8))) unsigned short u16x8;
typedef __attribute__((ext_vector_type(4))) float f32x4;

__device__ __forceinline__ unsigned short f2b(float f) {
  __hip_bfloat16 h = __float2bfloat16(f);
  union { __hip_bfloat16 b; unsigned short u; } cv;
  cv.b = h;
  return cv.u;
}
__device__ __forceinline__ float b2f(unsigned short u) {
  union { unsigned int i; float f; } cv;
  cv.i = ((unsigned int)u) << 16;
  return cv.f;
}

// async global -> LDS: wave-uniform LDS base, lane i lands at base + i*16B
__device__ __forceinline__ void load_lds16(const void* g, void* l) {
  __builtin_amdgcn_global_load_lds(
      (const __attribute__((address_space(1))) unsigned int*)g,
      (__attribute__((address_space(3))) unsigned int*)l, 16, 0, 0);
}

// ================= fused conversion: x -> xb,xT  and 6 weights -> Wb,WbT =================
__device__ __forceinline__ void cvt_tile(const float* __restrict__ src, int lds_,
                                         unsigned short* __restrict__ dst, int ldd,
                                         unsigned short* __restrict__ dstT, int ldt,
                                         int n0, int c0) {
  __shared__ unsigned short tile[64][66];
  const int t  = threadIdx.x;
  const int r  = t >> 2;
  const int cq = (t & 3) * 16;

  unsigned short loc[16];
  #pragma unroll
  for (int i = 0; i < 4; ++i) {
    float4 v = *reinterpret_cast<const float4*>(&src[(size_t)(n0 + r) * lds_ + c0 + cq + i * 4]);
    loc[i*4+0] = f2b(v.x); loc[i*4+1] = f2b(v.y); loc[i*4+2] = f2b(v.z); loc[i*4+3] = f2b(v.w);
  }
  {
    u16x8 a, b;
    #pragma unroll
    for (int i = 0; i < 8; ++i) { a[i] = loc[i]; b[i] = loc[8+i]; }
    unsigned short* p = &dst[(size_t)(n0 + r) * ldd + c0 + cq];
    *reinterpret_cast<u16x8*>(p)     = a;
    *reinterpret_cast<u16x8*>(p + 8) = b;
  }
  #pragma unroll
  for (int i = 0; i < 8; ++i) {
    ushort2 w2; w2.x = loc[2*i]; w2.y = loc[2*i+1];
    *reinterpret_cast<ushort2*>(&tile[r][cq + 2*i]) = w2;
  }
  __syncthreads();
  const int c  = t >> 2;
  const int ng = (t & 3) * 16;
  unsigned short o[16];
  #pragma unroll
  for (int i = 0; i < 16; ++i) o[i] = tile[ng + i][c];
  u16x8 a, b;
  #pragma unroll
  for (int i = 0; i < 8; ++i) { a[i] = o[i]; b[i] = o[8+i]; }
  unsigned short* p = &dstT[(size_t)(c0 + c) * ldt + n0 + ng];
  *reinterpret_cast<u16x8*>(p)     = a;
  *reinterpret_cast<u16x8*>(p + 8) = b;
}

__global__ __launch_bounds__(256) void k_cvt_all(const float* __restrict__ x,
                                                 const float* __restrict__ w0, const float* __restrict__ w1,
                                                 const float* __restrict__ w2, const float* __restrict__ w3,
                                                 const float* __restrict__ w4, const float* __restrict__ w5,
                                                 unsigned short* __restrict__ xb,
                                                 unsigned short* __restrict__ xT,
                                                 unsigned short* __restrict__ Wb,
                                                 unsigned short* __restrict__ WbT) {
  const int b = blockIdx.x;
  if (b < 1024) {
    cvt_tile(x, D_FULL, xb, D_FULL, xT, N_ROWS, (b >> 4) * 64, (b & 15) * 64);
  } else {
    const int b2 = b - 1024;
    const int z = b2 >> 6, t = b2 & 63;
    const float* w;
    switch (z) {
      case 0: w = w0; break; case 1: w = w1; break; case 2: w = w2; break;
      case 3: w = w3; break; case 4: w = w4; break; default: w = w5; break;
    }
    const size_t HH = (size_t)DHALF * DHALF;
    cvt_tile(w, DHALF, Wb + z * HH, DHALF, WbT + z * HH, DHALF, (t >> 3) * 64, (t & 7) * 64);
  }
}

// ================= gram partials + P, one launch =================
// z < 32 : Gp[z] = X_h(chunk s)^T X_h(chunk s), h=z>>4, s=z&15, kLen=256, lda=4096
// z >= 32: P_h = WqT_h * (WkT_h)^T, h=z-32, kLen=512, lda=512
__global__ __launch_bounds__(256) void k_gp(const unsigned short* __restrict__ xT,
                                            const unsigned short* __restrict__ WbT,
                                            unsigned short* __restrict__ Gp,
                                            unsigned short* __restrict__ P) {
  const int z = blockIdx.z;
  const unsigned short* Ab;
  const unsigned short* Bb;
  unsigned short* Cb;
  int lda, nt;
  const long long HH = 262144;
  if (z < 32) {
    const int h = z >> 4, s = z & 15;
    Ab = xT + (size_t)h * DHALF * N_ROWS + s * (N_ROWS / GSPLIT);
    Bb = Ab;
    Cb = Gp + (size_t)z * HH;
    lda = N_ROWS; nt = (N_ROWS / GSPLIT) >> 5;   // 8
  } else {
    const int h = z - 32;
    Ab = WbT + (size_t)h * HH;
    Bb = WbT + (size_t)(2 + h) * HH;
    Cb = P + (size_t)h * HH;
    lda = DHALF; nt = DHALF >> 5;                // 16
  }
  const int n0 = blockIdx.x * 128;
  const int m0 = blockIdx.y * 128;

  __shared__ __align__(16) unsigned short lds[2][2][128 * 32];

  const int tid  = threadIdx.x;
  const int lane = tid & 63;
  const int wave = tid >> 6;
  const int wm = (wave >> 1) * 64;
  const int wn = (wave & 1) * 64;
  const int fr = lane & 15;
  const int kg = (lane >> 4) * 8;

  const int srow = wave * 32 + (lane >> 2);
  const int scol = (lane & 3) * 8;
  const unsigned short* gA0 = Ab + (size_t)(m0 + srow) * lda + scol;
  const unsigned short* gA1 = gA0 + (size_t)16 * lda;
  const unsigned short* gB0 = Bb + (size_t)(n0 + srow) * lda + scol;
  const unsigned short* gB1 = gB0 + (size_t)16 * lda;
  const int stOff = wave * 1024;

  f32x4 acc[4][4] = {};

  auto STAGE = [&](int buf, int kofs) {
    load_lds16(gA0 + kofs, &lds[buf][0][stOff]);
    load_lds16(gA1 + kofs, &lds[buf][0][stOff + 512]);
    load_lds16(gB0 + kofs, &lds[buf][1][stOff]);
    load_lds16(gB1 + kofs, &lds[buf][1][stOff + 512]);
  };
  auto COMPUTE = [&](int buf) {
    const unsigned short* la = &lds[buf][0][0];
    const unsigned short* lb = &lds[buf][1][0];
    bf16x8 af[4], bf[4];
    #pragma unroll
    for (int f = 0; f < 4; ++f) {
      af[f] = *reinterpret_cast<const bf16x8*>(&la[(wm + f * 16 + fr) * 32 + kg]);
      bf[f] = *reinterpret_cast<const bf16x8*>(&lb[(wn + f * 16 + fr) * 32 + kg]);
    }
    #pragma unroll
    for (int fm = 0; fm < 4; ++fm)
      #pragma unroll
      for (int fn = 0; fn < 4; ++fn)
        acc[fm][fn] = __builtin_amdgcn_mfma_f32_16x16x32_bf16(af[fm], bf[fn], acc[fm][fn], 0, 0, 0);
  };

  STAGE(0, 0);
  __syncthreads();
  for (int t = 0; t < nt - 1; ++t) {
    STAGE((t + 1) & 1, (t + 1) * 32);
    COMPUTE(t & 1);
    __syncthreads();
  }
  COMPUTE((nt - 1) & 1);

  #pragma unroll
  for (int fm = 0; fm < 4; ++fm)
    #pragma unroll
    for (int fn = 0; fn < 4; ++fn)
      #pragma unroll
      for (int r = 0; r < 4; ++r) {
        int row = m0 + wm + fm * 16 + (lane >> 4) * 4 + r;
        int col = n0 + wn + fn * 16 + fr;
        Cb[(size_t)row * DHALF + col] = f2b(acc[fm][fn][r]);
      }
}

// ================= reduce bf16 partials -> G bf16 [2][512][512] =================
__global__ __launch_bounds__(256) void k_gred(const unsigned short* __restrict__ Gp,
                                              unsigned short* __restrict__ G) {
  int gid = blockIdx.x * 256 + threadIdx.x;   // 0..65535
  int h = gid >> 15;
  size_t e = (size_t)(gid & 32767) * 8;
  size_t base = (size_t)h * GSPLIT * (DHALF * DHALF) + e;
  float sum[8] = {};
  #pragma unroll
  for (int s = 0; s < GSPLIT; ++s) {
    u16x8 v = *reinterpret_cast<const u16x8*>(&Gp[base + (size_t)s * (DHALF * DHALF)]);
    #pragma unroll
    for (int i = 0; i < 8; ++i) sum[i] += b2f(v[i]);
  }
  u16x8 o;
  #pragma unroll
  for (int i = 0; i < 8; ++i) o[i] = f2b(sum[i]);
  *reinterpret_cast<u16x8*>(&G[(size_t)h * (DHALF * DHALF) + e]) = o;
}

// ================= small GEMM 512^3: C[m][n] = sum_k A[m][k]*B[n][k], bf16 in/out =================
__global__ __launch_bounds__(256) void k_s(const unsigned short* __restrict__ A,
                                           const unsigned short* __restrict__ B,
                                           unsigned short* __restrict__ C,
                                           long long hA, long long hB, long long hC) {
  const int h = blockIdx.z;
  const unsigned short* Ab = A + (size_t)h * hA;
  const unsigned short* Bb = B + (size_t)h * hB;
  unsigned short* Cb = C + (size_t)h * hC;
  const int n0 = blockIdx.x * 64;
  const int m0 = blockIdx.y * 64;

  __shared__ __align__(16) unsigned short lds[2][2][4][64 * 32];

  const int tid  = threadIdx.x;
  const int lane = tid & 63;
  const int wave = tid >> 6;
  const int wm = (wave >> 1) * 32;
  const int wn = (wave & 1) * 32;
  const int fr = lane & 15;
  const int kg = (lane >> 4) * 8;

  const int srow = lane >> 2;
  const int scol = (lane & 3) * 8;
  const unsigned short* gA = Ab + (size_t)(m0 + srow) * DHALF + wave * 32 + scol;
  const unsigned short* gB = Bb + (size_t)(n0 + srow) * DHALF + wave * 32 + scol;

  f32x4 acc[2][2] = {};

  auto STAGE = [&](int buf, int kofs) {
    #pragma unroll
    for (int j = 0; j < 4; ++j) {
      load_lds16(gA + kofs + j * 16 * DHALF, &lds[buf][0][wave][j * 512]);
      load_lds16(gB + kofs + j * 16 * DHALF, &lds[buf][1][wave][j * 512]);
    }
  };
  auto COMPUTE = [&](int buf) {
    #pragma unroll
    for (int p = 0; p < 4; ++p) {
      bf16x8 a0 = *reinterpret_cast<const bf16x8*>(&lds[buf][0][p][(wm + fr) * 32 + kg]);
      bf16x8 a1 = *reinterpret_cast<const bf16x8*>(&lds[buf][0][p][(wm + 16 + fr) * 32 + kg]);
      bf16x8 b0 = *reinterpret_cast<const bf16x8*>(&lds[buf][1][p][(wn + fr) * 32 + kg]);
      bf16x8 b1 = *reinterpret_cast<const bf16x8*>(&lds[buf][1][p][(wn + 16 + fr) * 32 + kg]);
      acc[0][0] = __builtin_amdgcn_mfma_f32_16x16x32_bf16(a0, b0, acc[0][0], 0, 0, 0);
      acc[0][1] = __builtin_amdgcn_mfma_f32_16x16x32_bf16(a0, b1, acc[0][1], 0, 0, 0);
      acc[1][0] = __builtin_amdgcn_mfma_f32_16x16x32_bf16(a1, b0, acc[1][0], 0, 0, 0);
      acc[1][1] = __builtin_amdgcn_mfma_f32_16x16x32_bf16(a1, b1, acc[1][1], 0, 0, 0);
    }
  };

  STAGE(0, 0);
  __syncthreads();
  for (int t = 0; t < 3; ++t) {
    STAGE((t + 1) & 1, (t + 1) * 128);
    COMPUTE(t & 1);
    __syncthreads();
  }
  COMPUTE(1);

  #pragma unroll
  for (int fm = 0; fm < 2; ++fm)
    #pragma unroll
    for (int fn = 0; fn < 2; ++fn)
      #pragma unroll
      for (int r = 0; r < 4; ++r) {
        int row = m0 + wm + fm * 16 + (lane >> 4) * 4 + r;
        int col = n0 + wn + fn * 16 + fr;
        Cb[(size_t)row * DHALF + col] = f2b(acc[fm][fn][r]);
      }
}

// ================= final: out[m][hoff+n] = sum_d xb[m][hoff+d]*MT[n][d], 128x64 tiles =================
__global__ __launch_bounds__(256) void k_final(const unsigned short* __restrict__ xb,
                                               const unsigned short* __restrict__ MT,
                                               float* __restrict__ out) {
  const int h = blockIdx.z;
  const unsigned short* MTh = MT + (size_t)h * 262144;
  const int hoff = h * DHALF;
  const int n0 = blockIdx.x * 64;
  const int m0 = blockIdx.y * 128;

  __shared__ __align__(16) unsigned short SH[12288];  // A dbuf 2x4096, B dbuf 2x2048 (24 KB)

  const int tid  = threadIdx.x;
  const int lane = tid & 63;
  const int wave = tid >> 6;
  const int wm = (wave >> 1) * 64;
  const int wn = (wave & 1) * 32;
  const int fr = lane & 15;
  const int kg = (lane >> 4) * 8;

  const int srow = wave * 32 + (lane >> 2);
  const int scol = (lane & 3) * 8;
  const unsigned short* gA0 = xb + (size_t)(m0 + srow) * D_FULL + hoff + scol;
  const unsigned short* gA1 = gA0 + (size_t)16 * D_FULL;
  const int brow = wave * 16 + (lane >> 2);
  const unsigned short* gB = MTh + (size_t)(n0 + brow) * DHALF + scol;

  f32x4 acc[4][2] = {};

  auto STAGE = [&](int buf, int kofs) {
    unsigned short* A = SH + buf * 4096;
    unsigned short* B = SH + 8192 + buf * 2048;
    load_lds16(gA0 + kofs, A + wave * 1024);
    load_lds16(gA1 + kofs, A + wave * 1024 + 512);
    load_lds16(gB + kofs, B + wave * 512);
  };
  auto COMPUTE = [&](int buf) {
    unsigned short* A = SH + buf * 4096;
    unsigned short* B = SH + 8192 + buf * 2048;
    bf16x8 af[4], bv[2];
    #pragma unroll
    for (int f = 0; f < 4; ++f)
      af[f] = *reinterpret_cast<const bf16x8*>(&A[(wm + f * 16 + fr) * 32 + kg]);
    #pragma unroll
    for (int f = 0; f < 2; ++f)
      bv[f] = *reinterpret_cast<const bf16x8*>(&B[(wn + f * 16 + fr) * 32 + kg]);
    #pragma unroll
    for (int fm = 0; fm < 4; ++fm)
      #pragma unroll
      for (int fn = 0; fn < 2; ++fn)
        acc[fm][fn] = __builtin_amdgcn_mfma_f32_16x16x32_bf16(af[fm], bv[fn], acc[fm][fn], 0, 0, 0);
  };

  STAGE(0, 0);
  __syncthreads();
  for (int t = 0; t < 15; ++t) {
    STAGE((t + 1) & 1, (t + 1) * 32);
    COMPUTE(t & 1);
    __syncthreads();
  }
  COMPUTE(1);

  #pragma unroll
  for (int fm = 0; fm < 4; ++fm)
    #pragma unroll
    for (int fn = 0; fn < 2; ++fn)
      #pragma unroll
      for (int r = 0; r < 4; ++r) {
        int row = m0 + wm + fm * 16 + (lane >> 4) * 4 + r;
        int col = hoff + n0 + wn + fn * 16 + fr;
        out[(size_t)row * D_FULL + col] = acc[fm][fn][r];
      }
}

extern "C" void kernel_launch(void* const* d_in, const int* in_sizes, int n_in,
                              void* d_out, int out_size, void* d_ws, size_t ws_size,
                              hipStream_t stream) {
  const float* x   = (const float*)d_in[0];
  const float* Wq1 = (const float*)d_in[1];
  const float* Wq2 = (const float*)d_in[2];
  const float* Wk1 = (const float*)d_in[3];
  const float* Wk2 = (const float*)d_in[4];
  const float* Wv1 = (const float*)d_in[5];
  const float* Wv2 = (const float*)d_in[6];
  float* out = (float*)d_out;

  // workspace layout (ushort elements), ~44 MB
  unsigned short* ws  = (unsigned short*)d_ws;
  unsigned short* xb  = ws;                    // [4096][1024]
  unsigned short* xT  = ws + 4194304;          // [1024][4096]
  unsigned short* Wb  = ws + 8388608;          // 6x[512][512]: q1,q2,k1,k2,v1,v2
  unsigned short* WbT = ws + 9961472;          // transposes, same order
  unsigned short* G   = ws + 11534336;         // [2][512][512]
  unsigned short* P   = ws + 12058624;         // [2][512][512]
  unsigned short* TT  = ws + 12582912;         // [2][512][512]
  unsigned short* MT  = ws + 13107200;         // [2][512][512]
  unsigned short* Gp  = ws + 13631488;         // [2*GSPLIT][512][512] bf16 partials

  const long long HH = 262144;

  k_cvt_all<<<1408, 256, 0, stream>>>(x, Wq1, Wq2, Wk1, Wk2, Wv1, Wv2, xb, xT, Wb, WbT);

  // gram partials (z 0..31) + P (z 32..33)
  k_gp<<<dim3(4, 4, 34), 256, 0, stream>>>(xT, WbT, Gp, P);

  k_gred<<<256, 256, 0, stream>>>(Gp, G);

  // TT = Wv * G  (G symmetric)
  k_s<<<dim3(8, 8, 2), 256, 0, stream>>>(Wb + 4 * HH, G, TT, HH, HH, HH);
  // MT = TT * P^T
  k_s<<<dim3(8, 8, 2), 256, 0, stream>>>(TT, P, MT, HH, HH, HH);

  // out = X_h * M_h
  k_final<<<dim3(8, 32, 2), 256, 0, stream>>>(xb, MT, out);
}

// Round 6
// 57.739 us; speedup vs baseline: 4.1919x; 1.0542x over previous
//
#include <hip/hip_runtime.h>
#include <hip/hip_bf16.h>

#define N_ROWS 4096
#define D_FULL 1024
#define DHALF  512
#define GSPLIT 16

typedef __attribute__((ext_vector_type(8))) short bf16x8;
typedef __attribute__((ext_vector_type(8))) unsigned short u16x8;
typedef __attribute__((ext_vector_type(4))) float f32x4;

__device__ __forceinline__ unsigned short f2b(float f) {
  __hip_bfloat16 h = __float2bfloat16(f);
  union { __hip_bfloat16 b; unsigned short u; } cv;
  cv.b = h;
  return cv.u;
}
__device__ __forceinline__ float b2f(unsigned short u) {
  union { unsigned int i; float f; } cv;
  cv.i = ((unsigned int)u) << 16;
  return cv.f;
}

// async global -> LDS: wave-uniform LDS base, lane i lands at base + i*16B
__device__ __forceinline__ void load_lds16(const void* g, void* l) {
  __builtin_amdgcn_global_load_lds(
      (const __attribute__((address_space(1))) unsigned int*)g,
      (__attribute__((address_space(3))) unsigned int*)l, 16, 0, 0);
}

// counted vmcnt wait (literal) — T4: never drain to 0 in the main loop
template<int N> __device__ __forceinline__ void vmwait() {
  if constexpr (N == 0)       asm volatile("s_waitcnt vmcnt(0)" ::: "memory");
  else if constexpr (N == 3)  asm volatile("s_waitcnt vmcnt(3)" ::: "memory");
  else if constexpr (N == 4)  asm volatile("s_waitcnt vmcnt(4)" ::: "memory");
  else if constexpr (N == 6)  asm volatile("s_waitcnt vmcnt(6)" ::: "memory");
  else if constexpr (N == 8)  asm volatile("s_waitcnt vmcnt(8)" ::: "memory");
  else                        asm volatile("s_waitcnt vmcnt(16)" ::: "memory");
}
// raw workgroup barrier, fenced against compiler code motion (rule #18 analog)
__device__ __forceinline__ void barx() {
  __builtin_amdgcn_sched_barrier(0);
  __builtin_amdgcn_s_barrier();
  __builtin_amdgcn_sched_barrier(0);
}
__device__ __forceinline__ int b3inc(int b) { return b == 2 ? 0 : b + 1; }

// ================= fused conversion: x -> xb,xT  and 6 weights -> Wb,WbT =================
__device__ __forceinline__ void cvt_tile(const float* __restrict__ src, int lds_,
                                         unsigned short* __restrict__ dst, int ldd,
                                         unsigned short* __restrict__ dstT, int ldt,
                                         int n0, int c0) {
  __shared__ unsigned short tile[64][66];
  const int t  = threadIdx.x;
  const int r  = t >> 2;
  const int cq = (t & 3) * 16;

  unsigned short loc[16];
  #pragma unroll
  for (int i = 0; i < 4; ++i) {
    float4 v = *reinterpret_cast<const float4*>(&src[(size_t)(n0 + r) * lds_ + c0 + cq + i * 4]);
    loc[i*4+0] = f2b(v.x); loc[i*4+1] = f2b(v.y); loc[i*4+2] = f2b(v.z); loc[i*4+3] = f2b(v.w);
  }
  {
    u16x8 a, b;
    #pragma unroll
    for (int i = 0; i < 8; ++i) { a[i] = loc[i]; b[i] = loc[8+i]; }
    unsigned short* p = &dst[(size_t)(n0 + r) * ldd + c0 + cq];
    *reinterpret_cast<u16x8*>(p)     = a;
    *reinterpret_cast<u16x8*>(p + 8) = b;
  }
  #pragma unroll
  for (int i = 0; i < 8; ++i) {
    ushort2 w2; w2.x = loc[2*i]; w2.y = loc[2*i+1];
    *reinterpret_cast<ushort2*>(&tile[r][cq + 2*i]) = w2;
  }
  __syncthreads();
  const int c  = t >> 2;
  const int ng = (t & 3) * 16;
  unsigned short o[16];
  #pragma unroll
  for (int i = 0; i < 16; ++i) o[i] = tile[ng + i][c];
  u16x8 a, b;
  #pragma unroll
  for (int i = 0; i < 8; ++i) { a[i] = o[i]; b[i] = o[8+i]; }
  unsigned short* p = &dstT[(size_t)(c0 + c) * ldt + n0 + ng];
  *reinterpret_cast<u16x8*>(p)     = a;
  *reinterpret_cast<u16x8*>(p + 8) = b;
}

__global__ __launch_bounds__(256) void k_cvt_all(const float* __restrict__ x,
                                                 const float* __restrict__ w0, const float* __restrict__ w1,
                                                 const float* __restrict__ w2, const float* __restrict__ w3,
                                                 const float* __restrict__ w4, const float* __restrict__ w5,
                                                 unsigned short* __restrict__ xb,
                                                 unsigned short* __restrict__ xT,
                                                 unsigned short* __restrict__ Wb,
                                                 unsigned short* __restrict__ WbT) {
  const int b = blockIdx.x;
  if (b < 1024) {
    cvt_tile(x, D_FULL, xb, D_FULL, xT, N_ROWS, (b >> 4) * 64, (b & 15) * 64);
  } else {
    const int b2 = b - 1024;
    const int z = b2 >> 6, t = b2 & 63;
    const float* w;
    switch (z) {
      case 0: w = w0; break; case 1: w = w1; break; case 2: w = w2; break;
      case 3: w = w3; break; case 4: w = w4; break; default: w = w5; break;
    }
    const size_t HH = (size_t)DHALF * DHALF;
    cvt_tile(w, DHALF, Wb + z * HH, DHALF, WbT + z * HH, DHALF, (t >> 3) * 64, (t & 7) * 64);
  }
}

// ================= gram partials + P, one launch; 3-buf depth-2 pipeline =================
// z < 32 : Gp[z] = X_h(chunk s)^T X_h(chunk s), h=z>>4, s=z&15, kLen=256, lda=4096, nt=8
// z >= 32: P_h = WqT_h * (WkT_h)^T, h=z-32, kLen=512, lda=512, nt=16
__global__ __launch_bounds__(256) void k_gp(const unsigned short* __restrict__ xT,
                                            const unsigned short* __restrict__ WbT,
                                            unsigned short* __restrict__ Gp,
                                            unsigned short* __restrict__ P) {
  const int z = blockIdx.z;
  const unsigned short* Ab;
  const unsigned short* Bb;
  unsigned short* Cb;
  int lda, nt;
  const long long HH = 262144;
  if (z < 32) {
    const int h = z >> 4, s = z & 15;
    Ab = xT + (size_t)h * DHALF * N_ROWS + s * (N_ROWS / GSPLIT);
    Bb = Ab;
    Cb = Gp + (size_t)z * HH;
    lda = N_ROWS; nt = (N_ROWS / GSPLIT) >> 5;   // 8
  } else {
    const int h = z - 32;
    Ab = WbT + (size_t)h * HH;
    Bb = WbT + (size_t)(2 + h) * HH;
    Cb = P + (size_t)h * HH;
    lda = DHALF; nt = DHALF >> 5;                // 16
  }
  const int n0 = blockIdx.x * 128;
  const int m0 = blockIdx.y * 128;

  __shared__ __align__(16) unsigned short lds[3][2][128 * 32];   // 48 KB

  const int tid  = threadIdx.x;
  const int lane = tid & 63;
  const int wave = tid >> 6;
  const int wm = (wave >> 1) * 64;
  const int wn = (wave & 1) * 64;
  const int fr = lane & 15;
  const int kg = (lane >> 4) * 8;

  const int srow = wave * 32 + (lane >> 2);
  const int scol = (lane & 3) * 8;
  const unsigned short* gA0 = Ab + (size_t)(m0 + srow) * lda + scol;
  const unsigned short* gA1 = gA0 + (size_t)16 * lda;
  const unsigned short* gB0 = Bb + (size_t)(n0 + srow) * lda + scol;
  const unsigned short* gB1 = gB0 + (size_t)16 * lda;
  const int stOff = wave * 1024;

  f32x4 acc[4][4] = {};

  auto STAGE = [&](int buf, int t) {         // 4 loads per wave (LPS=4)
    const int kofs = t * 32;
    load_lds16(gA0 + kofs, &lds[buf][0][stOff]);
    load_lds16(gA1 + kofs, &lds[buf][0][stOff + 512]);
    load_lds16(gB0 + kofs, &lds[buf][1][stOff]);
    load_lds16(gB1 + kofs, &lds[buf][1][stOff + 512]);
  };
  auto COMPUTE = [&](int buf) {
    const unsigned short* la = &lds[buf][0][0];
    const unsigned short* lb = &lds[buf][1][0];
    bf16x8 af[4], bf[4];
    #pragma unroll
    for (int f = 0; f < 4; ++f) {
      af[f] = *reinterpret_cast<const bf16x8*>(&la[(wm + f * 16 + fr) * 32 + kg]);
      bf[f] = *reinterpret_cast<const bf16x8*>(&lb[(wn + f * 16 + fr) * 32 + kg]);
    }
    #pragma unroll
    for (int fm = 0; fm < 4; ++fm)
      #pragma unroll
      for (int fn = 0; fn < 4; ++fn)
        acc[fm][fn] = __builtin_amdgcn_mfma_f32_16x16x32_bf16(af[fm], bf[fn], acc[fm][fn], 0, 0, 0);
  };

  STAGE(0, 0); STAGE(1, 1);
  int bufS = 2, bufC = 0;
  for (int t = 0; t < nt - 2; ++t) {
    STAGE(bufS, t + 2); bufS = b3inc(bufS);
    vmwait<8>(); barx();
    COMPUTE(bufC); bufC = b3inc(bufC);
    barx();
  }
  vmwait<4>(); barx();
  COMPUTE(bufC); bufC = b3inc(bufC);
  vmwait<0>(); barx();
  COMPUTE(bufC);

  #pragma unroll
  for (int fm = 0; fm < 4; ++fm)
    #pragma unroll
    for (int fn = 0; fn < 4; ++fn)
      #pragma unroll
      for (int r = 0; r < 4; ++r) {
        int row = m0 + wm + fm * 16 + (lane >> 4) * 4 + r;
        int col = n0 + wn + fn * 16 + fr;
        Cb[(size_t)row * DHALF + col] = f2b(acc[fm][fn][r]);
      }
}

// ================= reduce bf16 partials -> G bf16 [2][512][512] =================
__global__ __launch_bounds__(256) void k_gred(const unsigned short* __restrict__ Gp,
                                              unsigned short* __restrict__ G) {
  int gid = blockIdx.x * 256 + threadIdx.x;   // 0..65535
  int h = gid >> 15;
  size_t e = (size_t)(gid & 32767) * 8;
  size_t base = (size_t)h * GSPLIT * (DHALF * DHALF) + e;
  float sum[8] = {};
  #pragma unroll
  for (int s = 0; s < GSPLIT; ++s) {
    u16x8 v = *reinterpret_cast<const u16x8*>(&Gp[base + (size_t)s * (DHALF * DHALF)]);
    #pragma unroll
    for (int i = 0; i < 8; ++i) sum[i] += b2f(v[i]);
  }
  u16x8 o;
  #pragma unroll
  for (int i = 0; i < 8; ++i) o[i] = f2b(sum[i]);
  *reinterpret_cast<u16x8*>(&G[(size_t)h * (DHALF * DHALF) + e]) = o;
}

// ================= small GEMM 512^3: 3-buf pipeline, BK=128 (4 panels), nt=4 =================
__global__ __launch_bounds__(256) void k_s(const unsigned short* __restrict__ A,
                                           const unsigned short* __restrict__ B,
                                           unsigned short* __restrict__ C,
                                           long long hA, long long hB, long long hC) {
  const int h = blockIdx.z;
  const unsigned short* Ab = A + (size_t)h * hA;
  const unsigned short* Bb = B + (size_t)h * hB;
  unsigned short* Cb = C + (size_t)h * hC;
  const int n0 = blockIdx.x * 64;
  const int m0 = blockIdx.y * 64;

  __shared__ __align__(16) unsigned short lds[3][2][4][64 * 32];   // 96 KB

  const int tid  = threadIdx.x;
  const int lane = tid & 63;
  const int wave = tid >> 6;
  const int wm = (wave >> 1) * 32;
  const int wn = (wave & 1) * 32;
  const int fr = lane & 15;
  const int kg = (lane >> 4) * 8;

  const int srow = lane >> 2;
  const int scol = (lane & 3) * 8;
  const unsigned short* gA = Ab + (size_t)(m0 + srow) * DHALF + wave * 32 + scol;
  const unsigned short* gB = Bb + (size_t)(n0 + srow) * DHALF + wave * 32 + scol;

  f32x4 acc[2][2] = {};

  auto STAGE = [&](int buf, int t) {          // 8 loads per wave (LPS=8)
    const int kofs = t * 128;
    #pragma unroll
    for (int j = 0; j < 4; ++j) {
      load_lds16(gA + kofs + j * 16 * DHALF, &lds[buf][0][wave][j * 512]);
      load_lds16(gB + kofs + j * 16 * DHALF, &lds[buf][1][wave][j * 512]);
    }
  };
  auto COMPUTE = [&](int buf) {
    #pragma unroll
    for (int p = 0; p < 4; ++p) {
      bf16x8 a0 = *reinterpret_cast<const bf16x8*>(&lds[buf][0][p][(wm + fr) * 32 + kg]);
      bf16x8 a1 = *reinterpret_cast<const bf16x8*>(&lds[buf][0][p][(wm + 16 + fr) * 32 + kg]);
      bf16x8 b0 = *reinterpret_cast<const bf16x8*>(&lds[buf][1][p][(wn + fr) * 32 + kg]);
      bf16x8 b1 = *reinterpret_cast<const bf16x8*>(&lds[buf][1][p][(wn + 16 + fr) * 32 + kg]);
      acc[0][0] = __builtin_amdgcn_mfma_f32_16x16x32_bf16(a0, b0, acc[0][0], 0, 0, 0);
      acc[0][1] = __builtin_amdgcn_mfma_f32_16x16x32_bf16(a0, b1, acc[0][1], 0, 0, 0);
      acc[1][0] = __builtin_amdgcn_mfma_f32_16x16x32_bf16(a1, b0, acc[1][0], 0, 0, 0);
      acc[1][1] = __builtin_amdgcn_mfma_f32_16x16x32_bf16(a1, b1, acc[1][1], 0, 0, 0);
    }
  };

  STAGE(0, 0); STAGE(1, 1);
  int bufS = 2, bufC = 0;
  for (int t = 0; t < 2; ++t) {               // nt = 4
    STAGE(bufS, t + 2); bufS = b3inc(bufS);
    vmwait<16>(); barx();
    COMPUTE(bufC); bufC = b3inc(bufC);
    barx();
  }
  vmwait<8>(); barx();
  COMPUTE(bufC); bufC = b3inc(bufC);
  vmwait<0>(); barx();
  COMPUTE(bufC);

  #pragma unroll
  for (int fm = 0; fm < 2; ++fm)
    #pragma unroll
    for (int fn = 0; fn < 2; ++fn)
      #pragma unroll
      for (int r = 0; r < 4; ++r) {
        int row = m0 + wm + fm * 16 + (lane >> 4) * 4 + r;
        int col = n0 + wn + fn * 16 + fr;
        Cb[(size_t)row * DHALF + col] = f2b(acc[fm][fn][r]);
      }
}

// ================= final: out[m][hoff+n] = sum_d xb[m][hoff+d]*MT[n][d]; 3-buf pipeline =================
__global__ __launch_bounds__(256) void k_final(const unsigned short* __restrict__ xb,
                                               const unsigned short* __restrict__ MT,
                                               float* __restrict__ out) {
  const int h = blockIdx.z;
  const unsigned short* MTh = MT + (size_t)h * 262144;
  const int hoff = h * DHALF;
  const int n0 = blockIdx.x * 64;
  const int m0 = blockIdx.y * 128;

  __shared__ __align__(16) unsigned short SH[3][6144];  // per buf: A 4096 + B 2048 (36 KB)

  const int tid  = threadIdx.x;
  const int lane = tid & 63;
  const int wave = tid >> 6;
  const int wm = (wave >> 1) * 64;
  const int wn = (wave & 1) * 32;
  const int fr = lane & 15;
  const int kg = (lane >> 4) * 8;

  const int srow = wave * 32 + (lane >> 2);
  const int scol = (lane & 3) * 8;
  const unsigned short* gA0 = xb + (size_t)(m0 + srow) * D_FULL + hoff + scol;
  const unsigned short* gA1 = gA0 + (size_t)16 * D_FULL;
  const int brow = wave * 16 + (lane >> 2);
  const unsigned short* gB = MTh + (size_t)(n0 + brow) * DHALF + scol;

  f32x4 acc[4][2] = {};

  auto STAGE = [&](int buf, int t) {          // 3 loads per wave (LPS=3)
    const int kofs = t * 32;
    unsigned short* Abuf = &SH[buf][0];
    unsigned short* Bbuf = &SH[buf][4096];
    load_lds16(gA0 + kofs, Abuf + wave * 1024);
    load_lds16(gA1 + kofs, Abuf + wave * 1024 + 512);
    load_lds16(gB + kofs, Bbuf + wave * 512);
  };
  auto COMPUTE = [&](int buf) {
    unsigned short* Abuf = &SH[buf][0];
    unsigned short* Bbuf = &SH[buf][4096];
    bf16x8 af[4], bv[2];
    #pragma unroll
    for (int f = 0; f < 4; ++f)
      af[f] = *reinterpret_cast<const bf16x8*>(&Abuf[(wm + f * 16 + fr) * 32 + kg]);
    #pragma unroll
    for (int f = 0; f < 2; ++f)
      bv[f] = *reinterpret_cast<const bf16x8*>(&Bbuf[(wn + f * 16 + fr) * 32 + kg]);
    #pragma unroll
    for (int fm = 0; fm < 4; ++fm)
      #pragma unroll
      for (int fn = 0; fn < 2; ++fn)
        acc[fm][fn] = __builtin_amdgcn_mfma_f32_16x16x32_bf16(af[fm], bv[fn], acc[fm][fn], 0, 0, 0);
  };

  STAGE(0, 0); STAGE(1, 1);
  int bufS = 2, bufC = 0;
  for (int t = 0; t < 14; ++t) {              // nt = 16
    STAGE(bufS, t + 2); bufS = b3inc(bufS);
    vmwait<6>(); barx();
    COMPUTE(bufC); bufC = b3inc(bufC);
    barx();
  }
  vmwait<3>(); barx();
  COMPUTE(bufC); bufC = b3inc(bufC);
  vmwait<0>(); barx();
  COMPUTE(bufC);

  #pragma unroll
  for (int fm = 0; fm < 4; ++fm)
    #pragma unroll
    for (int fn = 0; fn < 2; ++fn)
      #pragma unroll
      for (int r = 0; r < 4; ++r) {
        int row = m0 + wm + fm * 16 + (lane >> 4) * 4 + r;
        int col = hoff + n0 + wn + fn * 16 + fr;
        out[(size_t)row * D_FULL + col] = acc[fm][fn][r];
      }
}

extern "C" void kernel_launch(void* const* d_in, const int* in_sizes, int n_in,
                              void* d_out, int out_size, void* d_ws, size_t ws_size,
                              hipStream_t stream) {
  const float* x   = (const float*)d_in[0];
  const float* Wq1 = (const float*)d_in[1];
  const float* Wq2 = (const float*)d_in[2];
  const float* Wk1 = (const float*)d_in[3];
  const float* Wk2 = (const float*)d_in[4];
  const float* Wv1 = (const float*)d_in[5];
  const float* Wv2 = (const float*)d_in[6];
  float* out = (float*)d_out;

  // workspace layout (ushort elements), ~44 MB
  unsigned short* ws  = (unsigned short*)d_ws;
  unsigned short* xb  = ws;                    // [4096][1024]
  unsigned short* xT  = ws + 4194304;          // [1024][4096]
  unsigned short* Wb  = ws + 8388608;          // 6x[512][512]: q1,q2,k1,k2,v1,v2
  unsigned short* WbT = ws + 9961472;          // transposes, same order
  unsigned short* G   = ws + 11534336;         // [2][512][512]
  unsigned short* P   = ws + 12058624;         // [2][512][512]
  unsigned short* TT  = ws + 12582912;         // [2][512][512]
  unsigned short* MT  = ws + 13107200;         // [2][512][512]
  unsigned short* Gp  = ws + 13631488;         // [2*GSPLIT][512][512] bf16 partials

  const long long HH = 262144;

  k_cvt_all<<<1408, 256, 0, stream>>>(x, Wq1, Wq2, Wk1, Wk2, Wv1, Wv2, xb, xT, Wb, WbT);

  // gram partials (z 0..31) + P (z 32..33)
  k_gp<<<dim3(4, 4, 34), 256, 0, stream>>>(xT, WbT, Gp, P);

  k_gred<<<256, 256, 0, stream>>>(Gp, G);

  // TT = Wv * G  (G symmetric)
  k_s<<<dim3(8, 8, 2), 256, 0, stream>>>(Wb + 4 * HH, G, TT, HH, HH, HH);
  // MT = TT * P^T
  k_s<<<dim3(8, 8, 2), 256, 0, stream>>>(TT, P, MT, HH, HH, HH);

  // out = X_h * M_h
  k_final<<<dim3(8, 32, 2), 256, 0, stream>>>(xb, MT, out);
}

// Round 7
// 50.426 us; speedup vs baseline: 4.7999x; 1.1450x over previous
//
#include <hip/hip_runtime.h>
#include <hip/hip_bf16.h>

#define N_ROWS 4096
#define D_FULL 1024
#define DHALF  512
#define GSPLIT 16

typedef __attribute__((ext_vector_type(8))) short bf16x8;
typedef __attribute__((ext_vector_type(8))) unsigned short u16x8;
typedef __attribute__((ext_vector_type(4))) float f32x4;

__device__ __forceinline__ unsigned short f2b(float f) {
  __hip_bfloat16 h = __float2bfloat16(f);
  union { __hip_bfloat16 b; unsigned short u; } cv;
  cv.b = h;
  return cv.u;
}
__device__ __forceinline__ float b2f(unsigned short u) {
  union { unsigned int i; float f; } cv;
  cv.i = ((unsigned int)u) << 16;
  return cv.f;
}

// async global -> LDS: wave-uniform LDS base, lane i lands at base + i*16B
__device__ __forceinline__ void load_lds16(const void* g, void* l) {
  __builtin_amdgcn_global_load_lds(
      (const __attribute__((address_space(1))) unsigned int*)g,
      (__attribute__((address_space(3))) unsigned int*)l, 16, 0, 0);
}

// counted vmcnt wait (literal) — T4: never drain to 0 in the main loop
template<int N> __device__ __forceinline__ void vmwait() {
  if constexpr (N == 0)       asm volatile("s_waitcnt vmcnt(0)" ::: "memory");
  else if constexpr (N == 3)  asm volatile("s_waitcnt vmcnt(3)" ::: "memory");
  else if constexpr (N == 4)  asm volatile("s_waitcnt vmcnt(4)" ::: "memory");
  else if constexpr (N == 6)  asm volatile("s_waitcnt vmcnt(6)" ::: "memory");
  else if constexpr (N == 8)  asm volatile("s_waitcnt vmcnt(8)" ::: "memory");
  else                        asm volatile("s_waitcnt vmcnt(16)" ::: "memory");
}
// raw workgroup barrier, fenced against compiler code motion
__device__ __forceinline__ void barx() {
  __builtin_amdgcn_sched_barrier(0);
  __builtin_amdgcn_s_barrier();
  __builtin_amdgcn_sched_barrier(0);
}
__device__ __forceinline__ int b3inc(int b) { return b == 2 ? 0 : b + 1; }

// ================= fused conversion =================
// dst / dstT may be null (skip that orientation); null-ness is block-uniform.
__device__ __forceinline__ void cvt_tile(const float* __restrict__ src, int lds_,
                                         unsigned short* __restrict__ dst, int ldd,
                                         unsigned short* __restrict__ dstT, int ldt,
                                         int n0, int c0) {
  __shared__ unsigned short tile[64][66];
  const int t  = threadIdx.x;
  const int r  = t >> 2;
  const int cq = (t & 3) * 16;

  unsigned short loc[16];
  #pragma unroll
  for (int i = 0; i < 4; ++i) {
    float4 v = *reinterpret_cast<const float4*>(&src[(size_t)(n0 + r) * lds_ + c0 + cq + i * 4]);
    loc[i*4+0] = f2b(v.x); loc[i*4+1] = f2b(v.y); loc[i*4+2] = f2b(v.z); loc[i*4+3] = f2b(v.w);
  }
  if (dst) {
    u16x8 a, b;
    #pragma unroll
    for (int i = 0; i < 8; ++i) { a[i] = loc[i]; b[i] = loc[8+i]; }
    unsigned short* p = &dst[(size_t)(n0 + r) * ldd + c0 + cq];
    *reinterpret_cast<u16x8*>(p)     = a;
    *reinterpret_cast<u16x8*>(p + 8) = b;
  }
  if (dstT) {
    #pragma unroll
    for (int i = 0; i < 8; ++i) {
      ushort2 w2; w2.x = loc[2*i]; w2.y = loc[2*i+1];
      *reinterpret_cast<ushort2*>(&tile[r][cq + 2*i]) = w2;
    }
    __syncthreads();
    const int c  = t >> 2;
    const int ng = (t & 3) * 16;
    unsigned short o[16];
    #pragma unroll
    for (int i = 0; i < 16; ++i) o[i] = tile[ng + i][c];
    u16x8 a, b;
    #pragma unroll
    for (int i = 0; i < 8; ++i) { a[i] = o[i]; b[i] = o[8+i]; }
    unsigned short* p = &dstT[(size_t)(c0 + c) * ldt + n0 + ng];
    *reinterpret_cast<u16x8*>(p)     = a;
    *reinterpret_cast<u16x8*>(p + 8) = b;
  }
}

__global__ __launch_bounds__(256) void k_cvt_all(const float* __restrict__ x,
                                                 const float* __restrict__ w0, const float* __restrict__ w1,
                                                 const float* __restrict__ w2, const float* __restrict__ w3,
                                                 const float* __restrict__ w4, const float* __restrict__ w5,
                                                 unsigned short* __restrict__ xb,
                                                 unsigned short* __restrict__ xT,
                                                 unsigned short* __restrict__ Wb,
                                                 unsigned short* __restrict__ WbT) {
  const int b = blockIdx.x;
  if (b < 1024) {
    cvt_tile(x, D_FULL, xb, D_FULL, xT, N_ROWS, (b >> 4) * 64, (b & 15) * 64);
  } else {
    const int b2 = b - 1024;
    const int z = b2 >> 6, t = b2 & 63;
    const float* w;
    switch (z) {
      case 0: w = w0; break; case 1: w = w1; break; case 2: w = w2; break;
      case 3: w = w3; break; case 4: w = w4; break; default: w = w5; break;
    }
    const size_t HH = (size_t)DHALF * DHALF;
    // q1,q2,k1,k2 (z<4): only transposed needed (P = WqT*(WkT)^T).
    // v1,v2 (z>=4): only plain needed (TT = Wv*G).
    unsigned short* d  = (z >= 4) ? (Wb  + z * HH) : nullptr;
    unsigned short* dT = (z <  4) ? (WbT + z * HH) : nullptr;
    cvt_tile(w, DHALF, d, DHALF, dT, DHALF, (t >> 3) * 64, (t & 7) * 64);
  }
}

// ================= gram partials + P, one launch; 3-buf depth-2 pipeline =================
// work z 0,1 : P_h = WqT_h * (WkT_h)^T, h=z, kLen=512, lda=512, nt=16  (dispatched FIRST)
// work z 2..33: Gp[z-2] = X_h(chunk s)^T X_h(chunk s), h=(z-2)>>4, s=(z-2)&15, kLen=256, nt=8
__global__ __launch_bounds__(256) void k_gp(const unsigned short* __restrict__ xT,
                                            const unsigned short* __restrict__ WbT,
                                            unsigned short* __restrict__ Gp,
                                            unsigned short* __restrict__ P) {
  // XCD-aware bijective swizzle: 544 blocks, 68 per XCD chunk
  const int o   = blockIdx.x + blockIdx.y * 4 + blockIdx.z * 16;
  const int swz = (o & 7) * 68 + (o >> 3);
  const int bx = swz & 3, by = (swz >> 2) & 3, bz = swz >> 4;

  const unsigned short* Ab;
  const unsigned short* Bb;
  unsigned short* Cb;
  int lda, nt;
  const long long HH = 262144;
  if (bz < 2) {
    const int h = bz;
    Ab = WbT + (size_t)h * HH;
    Bb = WbT + (size_t)(2 + h) * HH;
    Cb = P + (size_t)h * HH;
    lda = DHALF; nt = DHALF >> 5;                // 16
  } else {
    const int zz = bz - 2;
    const int h = zz >> 4, s = zz & 15;
    Ab = xT + (size_t)h * DHALF * N_ROWS + s * (N_ROWS / GSPLIT);
    Bb = Ab;
    Cb = Gp + (size_t)zz * HH;
    lda = N_ROWS; nt = (N_ROWS / GSPLIT) >> 5;   // 8
  }
  const int n0 = bx * 128;
  const int m0 = by * 128;

  __shared__ __align__(16) unsigned short lds[3][2][128 * 32];   // 48 KB

  const int tid  = threadIdx.x;
  const int lane = tid & 63;
  const int wave = tid >> 6;
  const int wm = (wave >> 1) * 64;
  const int wn = (wave & 1) * 64;
  const int fr = lane & 15;
  const int kg = (lane >> 4) * 8;

  const int srow = wave * 32 + (lane >> 2);
  const int scol = (lane & 3) * 8;
  const unsigned short* gA0 = Ab + (size_t)(m0 + srow) * lda + scol;
  const unsigned short* gA1 = gA0 + (size_t)16 * lda;
  const unsigned short* gB0 = Bb + (size_t)(n0 + srow) * lda + scol;
  const unsigned short* gB1 = gB0 + (size_t)16 * lda;
  const int stOff = wave * 1024;

  f32x4 acc[4][4] = {};

  auto STAGE = [&](int buf, int t) {         // 4 loads per wave (LPS=4)
    const int kofs = t * 32;
    load_lds16(gA0 + kofs, &lds[buf][0][stOff]);
    load_lds16(gA1 + kofs, &lds[buf][0][stOff + 512]);
    load_lds16(gB0 + kofs, &lds[buf][1][stOff]);
    load_lds16(gB1 + kofs, &lds[buf][1][stOff + 512]);
  };
  auto COMPUTE = [&](int buf) {
    const unsigned short* la = &lds[buf][0][0];
    const unsigned short* lb = &lds[buf][1][0];
    bf16x8 af[4], bf[4];
    #pragma unroll
    for (int f = 0; f < 4; ++f) {
      af[f] = *reinterpret_cast<const bf16x8*>(&la[(wm + f * 16 + fr) * 32 + kg]);
      bf[f] = *reinterpret_cast<const bf16x8*>(&lb[(wn + f * 16 + fr) * 32 + kg]);
    }
    #pragma unroll
    for (int fm = 0; fm < 4; ++fm)
      #pragma unroll
      for (int fn = 0; fn < 4; ++fn)
        acc[fm][fn] = __builtin_amdgcn_mfma_f32_16x16x32_bf16(af[fm], bf[fn], acc[fm][fn], 0, 0, 0);
  };

  STAGE(0, 0); STAGE(1, 1);
  int bufS = 2, bufC = 0;
  for (int t = 0; t < nt - 2; ++t) {
    STAGE(bufS, t + 2); bufS = b3inc(bufS);
    vmwait<8>(); barx();
    COMPUTE(bufC); bufC = b3inc(bufC);
    barx();
  }
  vmwait<4>(); barx();
  COMPUTE(bufC); bufC = b3inc(bufC);
  vmwait<0>(); barx();
  COMPUTE(bufC);

  #pragma unroll
  for (int fm = 0; fm < 4; ++fm)
    #pragma unroll
    for (int fn = 0; fn < 4; ++fn)
      #pragma unroll
      for (int r = 0; r < 4; ++r) {
        int row = m0 + wm + fm * 16 + (lane >> 4) * 4 + r;
        int col = n0 + wn + fn * 16 + fr;
        Cb[(size_t)row * DHALF + col] = f2b(acc[fm][fn][r]);
      }
}

// ================= reduce bf16 partials -> G bf16 [2][512][512] =================
__global__ __launch_bounds__(256) void k_gred(const unsigned short* __restrict__ Gp,
                                              unsigned short* __restrict__ G) {
  int gid = blockIdx.x * 256 + threadIdx.x;   // 0..65535
  int h = gid >> 15;
  size_t e = (size_t)(gid & 32767) * 8;
  size_t base = (size_t)h * GSPLIT * (DHALF * DHALF) + e;
  float sum[8] = {};
  #pragma unroll
  for (int s = 0; s < GSPLIT; ++s) {
    u16x8 v = *reinterpret_cast<const u16x8*>(&Gp[base + (size_t)s * (DHALF * DHALF)]);
    #pragma unroll
    for (int i = 0; i < 8; ++i) sum[i] += b2f(v[i]);
  }
  u16x8 o;
  #pragma unroll
  for (int i = 0; i < 8; ++i) o[i] = f2b(sum[i]);
  *reinterpret_cast<u16x8*>(&G[(size_t)h * (DHALF * DHALF) + e]) = o;
}

// ================= small GEMM 512^3: 3-buf pipeline, BK=128 (4 panels), nt=4 =================
__global__ __launch_bounds__(256) void k_s(const unsigned short* __restrict__ A,
                                           const unsigned short* __restrict__ B,
                                           unsigned short* __restrict__ C,
                                           long long hA, long long hB, long long hC) {
  // XCD swizzle: 128 blocks, 16 per XCD
  const int o   = blockIdx.x + blockIdx.y * 8 + blockIdx.z * 64;
  const int swz = (o & 7) * 16 + (o >> 3);
  const int bx = swz & 7, by = (swz >> 3) & 7, bz = swz >> 6;

  const unsigned short* Ab = A + (size_t)bz * hA;
  const unsigned short* Bb = B + (size_t)bz * hB;
  unsigned short* Cb = C + (size_t)bz * hC;
  const int n0 = bx * 64;
  const int m0 = by * 64;

  __shared__ __align__(16) unsigned short lds[3][2][4][64 * 32];   // 96 KB

  const int tid  = threadIdx.x;
  const int lane = tid & 63;
  const int wave = tid >> 6;
  const int wm = (wave >> 1) * 32;
  const int wn = (wave & 1) * 32;
  const int fr = lane & 15;
  const int kg = (lane >> 4) * 8;

  const int srow = lane >> 2;
  const int scol = (lane & 3) * 8;
  const unsigned short* gA = Ab + (size_t)(m0 + srow) * DHALF + wave * 32 + scol;
  const unsigned short* gB = Bb + (size_t)(n0 + srow) * DHALF + wave * 32 + scol;

  f32x4 acc[2][2] = {};

  auto STAGE = [&](int buf, int t) {          // 8 loads per wave (LPS=8)
    const int kofs = t * 128;
    #pragma unroll
    for (int j = 0; j < 4; ++j) {
      load_lds16(gA + kofs + j * 16 * DHALF, &lds[buf][0][wave][j * 512]);
      load_lds16(gB + kofs + j * 16 * DHALF, &lds[buf][1][wave][j * 512]);
    }
  };
  auto COMPUTE = [&](int buf) {
    #pragma unroll
    for (int p = 0; p < 4; ++p) {
      bf16x8 a0 = *reinterpret_cast<const bf16x8*>(&lds[buf][0][p][(wm + fr) * 32 + kg]);
      bf16x8 a1 = *reinterpret_cast<const bf16x8*>(&lds[buf][0][p][(wm + 16 + fr) * 32 + kg]);
      bf16x8 b0 = *reinterpret_cast<const bf16x8*>(&lds[buf][1][p][(wn + fr) * 32 + kg]);
      bf16x8 b1 = *reinterpret_cast<const bf16x8*>(&lds[buf][1][p][(wn + 16 + fr) * 32 + kg]);
      acc[0][0] = __builtin_amdgcn_mfma_f32_16x16x32_bf16(a0, b0, acc[0][0], 0, 0, 0);
      acc[0][1] = __builtin_amdgcn_mfma_f32_16x16x32_bf16(a0, b1, acc[0][1], 0, 0, 0);
      acc[1][0] = __builtin_amdgcn_mfma_f32_16x16x32_bf16(a1, b0, acc[1][0], 0, 0, 0);
      acc[1][1] = __builtin_amdgcn_mfma_f32_16x16x32_bf16(a1, b1, acc[1][1], 0, 0, 0);
    }
  };

  STAGE(0, 0); STAGE(1, 1);
  int bufS = 2, bufC = 0;
  for (int t = 0; t < 2; ++t) {               // nt = 4
    STAGE(bufS, t + 2); bufS = b3inc(bufS);
    vmwait<16>(); barx();
    COMPUTE(bufC); bufC = b3inc(bufC);
    barx();
  }
  vmwait<8>(); barx();
  COMPUTE(bufC); bufC = b3inc(bufC);
  vmwait<0>(); barx();
  COMPUTE(bufC);

  #pragma unroll
  for (int fm = 0; fm < 2; ++fm)
    #pragma unroll
    for (int fn = 0; fn < 2; ++fn)
      #pragma unroll
      for (int r = 0; r < 4; ++r) {
        int row = m0 + wm + fm * 16 + (lane >> 4) * 4 + r;
        int col = n0 + wn + fn * 16 + fr;
        Cb[(size_t)row * DHALF + col] = f2b(acc[fm][fn][r]);
      }
}

// ================= final: out[m][hoff+n] = sum_d xb[m][hoff+d]*MT[n][d]; 3-buf pipeline =================
__global__ __launch_bounds__(256) void k_final(const unsigned short* __restrict__ xb,
                                               const unsigned short* __restrict__ MT,
                                               float* __restrict__ out) {
  // XCD swizzle: 512 blocks, 64 per XCD -> each XCD keeps 8 A-panels + MT half in L2
  const int o   = blockIdx.x + blockIdx.y * 8 + blockIdx.z * 256;
  const int swz = (o & 7) * 64 + (o >> 3);
  const int bx = swz & 7, by = (swz >> 3) & 31, bz = swz >> 8;

  const unsigned short* MTh = MT + (size_t)bz * 262144;
  const int hoff = bz * DHALF;
  const int n0 = bx * 64;
  const int m0 = by * 128;

  __shared__ __align__(16) unsigned short SH[3][6144];  // per buf: A 4096 + B 2048 (36 KB)

  const int tid  = threadIdx.x;
  const int lane = tid & 63;
  const int wave = tid >> 6;
  const int wm = (wave >> 1) * 64;
  const int wn = (wave & 1) * 32;
  const int fr = lane & 15;
  const int kg = (lane >> 4) * 8;

  const int srow = wave * 32 + (lane >> 2);
  const int scol = (lane & 3) * 8;
  const unsigned short* gA0 = xb + (size_t)(m0 + srow) * D_FULL + hoff + scol;
  const unsigned short* gA1 = gA0 + (size_t)16 * D_FULL;
  const int brow = wave * 16 + (lane >> 2);
  const unsigned short* gB = MTh + (size_t)(n0 + brow) * DHALF + scol;

  f32x4 acc[4][2] = {};

  auto STAGE = [&](int buf, int t) {          // 3 loads per wave (LPS=3)
    const int kofs = t * 32;
    unsigned short* Abuf = &SH[buf][0];
    unsigned short* Bbuf = &SH[buf][4096];
    load_lds16(gA0 + kofs, Abuf + wave * 1024);
    load_lds16(gA1 + kofs, Abuf + wave * 1024 + 512);
    load_lds16(gB + kofs, Bbuf + wave * 512);
  };
  auto COMPUTE = [&](int buf) {
    unsigned short* Abuf = &SH[buf][0];
    unsigned short* Bbuf = &SH[buf][4096];
    bf16x8 af[4], bv[2];
    #pragma unroll
    for (int f = 0; f < 4; ++f)
      af[f] = *reinterpret_cast<const bf16x8*>(&Abuf[(wm + f * 16 + fr) * 32 + kg]);
    #pragma unroll
    for (int f = 0; f < 2; ++f)
      bv[f] = *reinterpret_cast<const bf16x8*>(&Bbuf[(wn + f * 16 + fr) * 32 + kg]);
    #pragma unroll
    for (int fm = 0; fm < 4; ++fm)
      #pragma unroll
      for (int fn = 0; fn < 2; ++fn)
        acc[fm][fn] = __builtin_amdgcn_mfma_f32_16x16x32_bf16(af[fm], bv[fn], acc[fm][fn], 0, 0, 0);
  };

  STAGE(0, 0); STAGE(1, 1);
  int bufS = 2, bufC = 0;
  for (int t = 0; t < 14; ++t) {              // nt = 16
    STAGE(bufS, t + 2); bufS = b3inc(bufS);
    vmwait<6>(); barx();
    COMPUTE(bufC); bufC = b3inc(bufC);
    barx();
  }
  vmwait<3>(); barx();
  COMPUTE(bufC); bufC = b3inc(bufC);
  vmwait<0>(); barx();
  COMPUTE(bufC);

  #pragma unroll
  for (int fm = 0; fm < 4; ++fm)
    #pragma unroll
    for (int fn = 0; fn < 2; ++fn)
      #pragma unroll
      for (int r = 0; r < 4; ++r) {
        int row = m0 + wm + fm * 16 + (lane >> 4) * 4 + r;
        int col = hoff + n0 + wn + fn * 16 + fr;
        out[(size_t)row * D_FULL + col] = acc[fm][fn][r];
      }
}

extern "C" void kernel_launch(void* const* d_in, const int* in_sizes, int n_in,
                              void* d_out, int out_size, void* d_ws, size_t ws_size,
                              hipStream_t stream) {
  const float* x   = (const float*)d_in[0];
  const float* Wq1 = (const float*)d_in[1];
  const float* Wq2 = (const float*)d_in[2];
  const float* Wk1 = (const float*)d_in[3];
  const float* Wk2 = (const float*)d_in[4];
  const float* Wv1 = (const float*)d_in[5];
  const float* Wv2 = (const float*)d_in[6];
  float* out = (float*)d_out;

  // workspace layout (ushort elements), ~44 MB
  unsigned short* ws  = (unsigned short*)d_ws;
  unsigned short* xb  = ws;                    // [4096][1024]
  unsigned short* xT  = ws + 4194304;          // [1024][4096]
  unsigned short* Wb  = ws + 8388608;          // 6x[512][512]: q1,q2,k1,k2,v1,v2 (only v written)
  unsigned short* WbT = ws + 9961472;          // transposes (only q,k written)
  unsigned short* G   = ws + 11534336;         // [2][512][512]
  unsigned short* P   = ws + 12058624;         // [2][512][512]
  unsigned short* TT  = ws + 12582912;         // [2][512][512]
  unsigned short* MT  = ws + 13107200;         // [2][512][512]
  unsigned short* Gp  = ws + 13631488;         // [2*GSPLIT][512][512] bf16 partials

  const long long HH = 262144;

  k_cvt_all<<<1408, 256, 0, stream>>>(x, Wq1, Wq2, Wk1, Wk2, Wv1, Wv2, xb, xT, Wb, WbT);

  // P (work-z 0,1, dispatched first) + gram partials (work-z 2..33)
  k_gp<<<dim3(4, 4, 34), 256, 0, stream>>>(xT, WbT, Gp, P);

  k_gred<<<256, 256, 0, stream>>>(Gp, G);

  // TT = Wv * G  (G symmetric)
  k_s<<<dim3(8, 8, 2), 256, 0, stream>>>(Wb + 4 * HH, G, TT, HH, HH, HH);
  // MT = TT * P^T
  k_s<<<dim3(8, 8, 2), 256, 0, stream>>>(TT, P, MT, HH, HH, HH);

  // out = X_h * M_h
  k_final<<<dim3(8, 32, 2), 256, 0, stream>>>(xb, MT, out);
}